// Round 12
// baseline (356.096 us; speedup 1.0000x reference)
//
#include <hip/hip_runtime.h>
#include <math.h>

// Min-sum BP LDPC decoder, LDS-resident messages, degree-sorted checks.
// SINGLE dispatch: setup (degree sort + padded layout) fused into bp_decode,
// recomputed per block with a FAST parallel scheme (unlike R8's serial-ballot
// disaster). One block = one batch element; padded arena (~160 KB) in LDS.
//
// R13 = R12's decode loop, BYTE-IDENTICAL (146.6 us, 64 VGPR, b64 checks,
// stride ≡ 2 mod 4, iter-0 peel, xor-sign, exact-degree dispatch) + fused
// fast setup, eliminating the 23 us setup dispatch (launch overhead + 1-CU
// kernel; harness charges ~28 us per extra dispatch, R7-calibrated):
//  - Coalesced flat mask scan: thread t reads elements t, t+1024, ... of
//    check_mask (96 independent L2-hot loads), LDS-atomic deg[c]++ per
//    nonzero. (R8's +137 us came from 256 SERIAL ballot wave-iterations,
//    each exposing full load latency — avoided entirely.)
//  - Closed-form padded bases per degree bin (stride s(d) depends only on
//    d): no per-check prefix scan. 64-bin hist -> packed prefix
//    (bin_start u16 | pad_base u16<<16).
//  - Fused scatter atomic: atomicAdd(&bins[d], 1 | s(d)<<16) returns
//    (ordinal, pad_base) in one op.
//  - Block-private nondeterministic layout: validity class hardware-proven
//    (R7: nondeterministic within-bin order PASSED; R8: per-block layouts
//    PASSED). Arithmetic untouched -> bit-exact.
//  - d_ws entirely unused; single launch; no memsets (graph-capture clean).
//  - HARD CONSTRAINTS unchanged: 64-VGPR allocator pin (R3/R9 — all new
//    state is short-lived), never reorder reference FP math (R6).
//  - Revert trigger: bp_decode > 170 us => per-block setup too slow,
//    return to R12's two-dispatch version.

#define BLOCK 1024
#define NV    8192          // N variables
#define MC    4096          // M checks
#define NE    32768         // E edges (N * DV, DV=4)
#define VPT   (NV / BLOCK)  // 8 vars per thread
#define CPT   (MC / BLOCK)  // 4 checks per thread
#define NITER 10
#define ALPHA 0.8f
#define CLAMP 20.0f
#define MSGW  40896         // padded arena words (159.9 KB)
#define SGNB  0x80000000

// stride: smallest s >= d with s ≡ 2 (mod 4)  [even base for b64 + banking]
__device__ __forceinline__ int pad_stride(int d) { return d + ((2 - (d & 3)) & 3); }

// ---------------- check updates (byte-identical to R12) ----------------
template<int D>
__device__ __forceinline__ void do_check_x(char* __restrict__ mb,
                                           int stB, int ssb, float pad)
{
    float x[D];
    constexpr int P = D / 2;
#pragma unroll
    for (int p = 0; p < P; ++p) {
        const float2 r = *(const float2*)(mb + stB + 8 * p);
        x[2 * p]     = r.x;
        x[2 * p + 1] = r.y;
    }
    if constexpr (D & 1)
        x[D - 1] = *(const float*)(mb + stB + 4 * (D - 1));

    float min1 = pad, min2 = pad;
    int sb = ssb;
#pragma unroll
    for (int j = 0; j < D; ++j) {
        sb ^= __float_as_int(x[j]);                     // sign parity (no -0.0)
        const float a = fabsf(x[j]);
        min2 = __builtin_amdgcn_fmed3f(min1, min2, a);  // uses OLD min1
        min1 = fminf(min1, a);
    }
    const float vm1 = ALPHA * min1;
    const float vm2 = ALPHA * min2;
#pragma unroll
    for (int p = 0; p < P; ++p) {
        const int j0 = 2 * p, j1 = 2 * p + 1;
        const float m0 = (fabsf(fabsf(x[j0]) - min1) < 1e-9f) ? vm2 : vm1;  // REF tie rule
        const float m1 = (fabsf(fabsf(x[j1]) - min1) < 1e-9f) ? vm2 : vm1;
        float2 w;
        w.x = __int_as_float(__float_as_int(m0) | ((sb ^ __float_as_int(x[j0])) & SGNB));
        w.y = __int_as_float(__float_as_int(m1) | ((sb ^ __float_as_int(x[j1])) & SGNB));
        *(float2*)(mb + stB + 8 * p) = w;
    }
    if constexpr (D & 1) {
        const int jt = D - 1;
        const float mt = (fabsf(fabsf(x[jt]) - min1) < 1e-9f) ? vm2 : vm1;
        *(float*)(mb + stB + 4 * jt) =
            __int_as_float(__float_as_int(mt) | ((sb ^ __float_as_int(x[jt])) & SGNB));
    }
}

template<int DMAX>
__device__ __forceinline__ void do_check(char* __restrict__ mb,
                                         int stB, int d, int ssb, float pad)
{
    float x[DMAX];
    float min1 = pad, min2 = pad;
    int sb = ssb;
#pragma unroll
    for (int j = 0; j < DMAX; ++j) {
        if (j >= d) break;
        x[j] = *(const float*)(mb + stB + 4 * j);
    }
#pragma unroll
    for (int j = 0; j < DMAX; ++j) {
        if (j >= d) break;
        sb ^= __float_as_int(x[j]);
        const float a = fabsf(x[j]);
        min2 = __builtin_amdgcn_fmed3f(min1, min2, a);
        min1 = fminf(min1, a);
    }
    const float vm1 = ALPHA * min1;
    const float vm2 = ALPHA * min2;
#pragma unroll
    for (int j = 0; j < DMAX; ++j) {
        if (j >= d) break;
        const float m = (fabsf(fabsf(x[j]) - min1) < 1e-9f) ? vm2 : vm1;
        *(float*)(mb + stB + 4 * j) =
            __int_as_float(__float_as_int(m) | ((sb ^ __float_as_int(x[j])) & SGNB));
    }
}

__device__ void do_check_big(char* __restrict__ mb,
                             int stB, int d, int ssb, float pad)
{
    float min1 = pad, min2 = pad;
    int sb = ssb;
    for (int j = 0; j < d; ++j) {
        const float xx = *(const float*)(mb + stB + 4 * j);
        sb ^= __float_as_int(xx);
        const float aa = fabsf(xx);
        min2 = __builtin_amdgcn_fmed3f(min1, min2, aa);
        min1 = fminf(min1, aa);
    }
    const float vm1 = ALPHA * min1;
    const float vm2 = ALPHA * min2;
    for (int j = 0; j < d; ++j) {
        const float xx = *(const float*)(mb + stB + 4 * j);
        const float m  = (fabsf(fabsf(xx) - min1) < 1e-9f) ? vm2 : vm1;
        *(float*)(mb + stB + 4 * j) =
            __int_as_float(__float_as_int(m) | ((sb ^ __float_as_int(xx)) & SGNB));
    }
}

__device__ __forceinline__ void check_dispatch(char* __restrict__ mb,
                                               int stB, int d, int ssb, float pad)
{
    if      (d == 8)  do_check_x<8>(mb, stB, ssb, pad);
    else if (d == 7)  do_check_x<7>(mb, stB, ssb, pad);
    else if (d == 9)  do_check_x<9>(mb, stB, ssb, pad);
    else if (d == 6)  do_check_x<6>(mb, stB, ssb, pad);
    else if (d == 10) do_check_x<10>(mb, stB, ssb, pad);
    else if (d == 5)  do_check_x<5>(mb, stB, ssb, pad);
    else if (d == 11) do_check_x<11>(mb, stB, ssb, pad);
    else if (d == 12) do_check_x<12>(mb, stB, ssb, pad);
    else if (d == 4)  do_check_x<4>(mb, stB, ssb, pad);
    else if (d <= 3)  do_check<3>(mb, stB, d, ssb, pad);
    else if (d <= 16) do_check<16>(mb, stB, d, ssb, pad);
    else              do_check_big(mb, stB, d, ssb, pad);
}

__global__ __launch_bounds__(BLOCK) __attribute__((amdgpu_waves_per_eu(4, 4)))
void bp_decode(const float* __restrict__ syndrome,    // (B, M)
               const float* __restrict__ llr_g,       // (B, N)
               const int*   __restrict__ var_adj,     // (N, 4)
               const int*   __restrict__ var_idx,     // (E,)
               const int*   __restrict__ check_adj,   // (M, max_dc)
               const float* __restrict__ check_mask,  // (M, max_dc)
               int max_dc,
               float* __restrict__ out,               // marginals | hard | converged
               int B)
{
    __shared__ float msg[MSGW];  // padded arena; sort scratch early, msgs later
    __shared__ float sh_e0;      // |vtc[edge 0]| snapshot for reference's pad
    __shared__ int   mism;

    const int b = blockIdx.x;
    const int t = threadIdx.x;
    char* mb = (char*)msg;
    int* arena = (int*)msg;

    // ======== fused fast setup (block-private, parallel) ========
    int* degL = arena;            // [0 .. MC)
    int* bins = arena + MC;       // [MC .. MC+64)  cnt -> packed prefix -> cursor
    int* rec1 = arena + MC + 64;  // [.. +MC)  pbase(16b) | deg<<16, sorted order
    int* rec2 = arena + 2 * MC + 64;  // [.. +MC)  original check index

    for (int i = t; i < MC + 64; i += BLOCK) arena[i] = 0;
    __syncthreads();

    // -- stage 1: degrees via coalesced flat scan + LDS atomics --
    {
        const int total = MC * max_dc;
        const int qs = BLOCK / max_dc, rs = BLOCK % max_dc;
        int c = t / max_dc, j = t % max_dc;       // one divide; then incremental
        for (int e = t; e < total; e += BLOCK) {
            if (check_mask[e] != 0.0f) atomicAdd(&degL[c], 1);
            c += qs; j += rs;
            if (j >= max_dc) { j -= max_dc; ++c; }
        }
    }
    __syncthreads();

    // -- stage 2: 64-bin degree histogram --
    int myd[CPT];
#pragma unroll
    for (int k = 0; k < CPT; ++k) {
        myd[k] = degL[t + k * BLOCK] & 63;
        atomicAdd(&bins[myd[k]], 1);
    }
    __syncthreads();

    // -- stage 3: packed prefix (bin_start u16 | pad_base u16<<16) --
    if (t == 0) {
        int cs = 0, ps = 0;
        for (int d = 0; d < 64; ++d) {
            const int cnt = bins[d];
            bins[d] = (cs & 0xFFFF) | (ps << 16);
            cs += cnt;
            ps += cnt * pad_stride(d);   // ps <= ~39k fits u16
        }
    }
    __syncthreads();

    // -- stage 4: scatter via fused ordinal+padbase atomic --
#pragma unroll
    for (int k = 0; k < CPT; ++k) {
        const int c = t + k * BLOCK;
        const int d = myd[k];
        const int old = atomicAdd(&bins[d], 1 | (pad_stride(d) << 16));
        const int pos = old & 0xFFFF;
        const int pb  = (old >> 16) & 0xFFFF;
        rec1[pos] = pb | (d << 16);
        rec2[pos] = c;
    }
    __syncthreads();

    // -- stage 5: strided readback of sorted records into registers --
    int cstB[CPT], dsb[CPT], stE[CPT];  // byte base; (deg<<1)|synbit; edge start
#pragma unroll
    for (int k = 0; k < CPT; ++k) {
        const int i = t + k * BLOCK;
        const int w = rec1[i];
        const int c = rec2[i];
        cstB[k] = (w & 0xFFFF) << 2;
        const int d  = w >> 16;
        const int sb = (syndrome[(size_t)b * MC + c] > 0.5f) ? 1 : 0;
        dsb[k] = (d << 1) | sb;
        stE[k] = check_adj[(size_t)c * max_dc];   // first edge (contiguous per check)
    }
    __syncthreads();   // all rec reads done; arena may be overwritten

    // -- stage 6: build posL[e] (edge -> padded slot) in arena[0..NE) --
#pragma unroll
    for (int k = 0; k < CPT; ++k) {
        const int d  = dsb[k] >> 1;
        const int pb = cstB[k] >> 2;
        const int st = stE[k];
        for (int j = 0; j < d; ++j)
            arena[st + j] = pb + j;
    }
    __syncthreads();

    // -- stage 7: edge-0 owner + var-side byte offsets + LLRs --
    const int  v0  = var_idx[0];
    const bool own = (t == (v0 & (BLOCK - 1)));   // thread that writes edge 0
    const int  e0B = arena[0] << 2;               // posL[0] as byte offset

    int   vsB[VPT][4];
    float llr[VPT];
#pragma unroll
    for (int k = 0; k < VPT; ++k) {
        const int v = t + k * BLOCK;
        const int4 a = ((const int4*)var_adj)[v];   // var degree is exactly 4
        vsB[k][0] = arena[a.x] << 2; vsB[k][1] = arena[a.y] << 2;
        vsB[k][2] = arena[a.z] << 2; vsB[k][3] = arena[a.w] << 2;
        llr[k] = llr_g[(size_t)b * NV + v];
    }
    __syncthreads();   // posL reads done (no zero-fill: iter 0 writes every
                       // edge slot; pad gaps are never read)

    // ======== decode loop (BYTE-IDENTICAL to R12) ========
    // -- iter 0 (peeled): ctv==0 -> vtc = clip(llr), write-only --
#pragma unroll
    for (int k = 0; k < VPT; ++k) {
        const float o = __builtin_amdgcn_fmed3f(llr[k], -CLAMP, CLAMP);
        *(float*)(mb + vsB[k][0]) = o;
        *(float*)(mb + vsB[k][1]) = o;
        *(float*)(mb + vsB[k][2]) = o;
        *(float*)(mb + vsB[k][3]) = o;
    }
    if (own) sh_e0 = fabsf(*(const float*)(mb + e0B)) + 1.0e6f;  // own write, RAW-ordered
    __syncthreads();
    {
        const float pad = sh_e0;
#pragma unroll
        for (int k = 0; k < CPT; ++k)
            check_dispatch(mb, cstB[k], dsb[k] >> 1, (dsb[k] & 1) << 31, pad);
    }
    __syncthreads();

    // -- iters 1..NITER-1 --
#pragma unroll 1
    for (int it = 1; it < NITER; ++it) {
#pragma unroll
        for (int k = 0; k < VPT; ++k) {
            const float c0 = *(const float*)(mb + vsB[k][0]);
            const float c1 = *(const float*)(mb + vsB[k][1]);
            const float c2 = *(const float*)(mb + vsB[k][2]);
            const float c3 = *(const float*)(mb + vsB[k][3]);
            const float tot  = ((c0 + c1) + c2) + c3;   // reference sum order
            const float bse  = llr[k] + tot;
            *(float*)(mb + vsB[k][0]) = __builtin_amdgcn_fmed3f(bse - c0, -CLAMP, CLAMP);
            *(float*)(mb + vsB[k][1]) = __builtin_amdgcn_fmed3f(bse - c1, -CLAMP, CLAMP);
            *(float*)(mb + vsB[k][2]) = __builtin_amdgcn_fmed3f(bse - c2, -CLAMP, CLAMP);
            *(float*)(mb + vsB[k][3]) = __builtin_amdgcn_fmed3f(bse - c3, -CLAMP, CLAMP);
        }
        if (own) sh_e0 = fabsf(*(const float*)(mb + e0B)) + 1.0e6f;   // own write, ordered
        __syncthreads();
        const float pad = sh_e0;

#pragma unroll
        for (int k = 0; k < CPT; ++k)
            check_dispatch(mb, cstB[k], dsb[k] >> 1, (dsb[k] & 1) << 31, pad);
        __syncthreads();
    }

    // ---- finale: marginals, hard decisions, convergence ----
    float marg[VPT], hard[VPT];
#pragma unroll
    for (int k = 0; k < VPT; ++k) {
        const float c0 = *(const float*)(mb + vsB[k][0]);
        const float c1 = *(const float*)(mb + vsB[k][1]);
        const float c2 = *(const float*)(mb + vsB[k][2]);
        const float c3 = *(const float*)(mb + vsB[k][3]);
        const float tot = ((c0 + c1) + c2) + c3;
        const float tl  = llr[k] + tot;
        const float mg  = 1.0f / (1.0f + expf(tl));   // sigmoid(-tl)
        marg[k] = mg;
        hard[k] = (mg > 0.5f) ? 1.0f : 0.0f;
    }
    if (t == 0) mism = 0;
    __syncthreads();   // all ctv reads done; safe to overwrite msg

    const size_t BN = (size_t)B * NV;
#pragma unroll
    for (int k = 0; k < VPT; ++k) {
        const int v = t + k * BLOCK;
        out[(size_t)b * NV + v]      = marg[k];        // output 0: marginals
        out[BN + (size_t)b * NV + v] = hard[k];        // output 1: hard_decision
        const float h = hard[k];                       // scatter hard bit to edges
        *(float*)(mb + vsB[k][0]) = h;
        *(float*)(mb + vsB[k][1]) = h;
        *(float*)(mb + vsB[k][2]) = h;
        *(float*)(mb + vsB[k][3]) = h;
    }
    __syncthreads();

    // syn_hat[c] = parity over the check's edges' hard bits; converged iff == syndrome
#pragma unroll
    for (int k = 0; k < CPT; ++k) {
        const int d  = dsb[k] >> 1;
        const int sb = dsb[k] & 1;
        int par = 0;
        for (int j = 0; j < d; ++j)
            par ^= (*(const float*)(mb + cstB[k] + 4 * j) != 0.0f) ? 1 : 0;
        if (par != sb) mism = 1;   // benign race: all writers store 1
    }
    __syncthreads();
    if (t == 0) out[2 * BN + b] = mism ? 0.0f : 1.0f;  // output 2: converged
}

extern "C" void kernel_launch(void* const* d_in, const int* in_sizes, int n_in,
                              void* d_out, int out_size, void* d_ws, size_t ws_size,
                              hipStream_t stream) {
    const float* syndrome   = (const float*)d_in[0];
    const float* llr        = (const float*)d_in[1];
    const int*   var_adj    = (const int*)d_in[2];
    // d_in[3] var_adj_mask: all ones (DV=4 exact) — unused
    const int*   check_adj  = (const int*)d_in[4];
    const float* check_mask = (const float*)d_in[5];
    const int*   var_idx    = (const int*)d_in[6];
    // d_in[7] pcm_dense — unused
    float* out = (float*)d_out;
    (void)d_ws; (void)ws_size;   // workspace unused: zero hazard

    const int B      = in_sizes[0] / MC;      // 256
    const int max_dc = in_sizes[4] / MC;

    bp_decode<<<B, BLOCK, 0, stream>>>(syndrome, llr, var_adj, var_idx,
                                       check_adj, check_mask, max_dc, out, B);
}

// Round 13
// 297.389 us; speedup vs baseline: 1.1974x; 1.1974x over previous
//
#include <hip/hip_runtime.h>
#include <math.h>

// Min-sum BP LDPC decoder, LDS-resident messages, degree-sorted checks.
// One block = one batch element; padded msg arena (~160 KB) lives in LDS.
//
// R14 = R12 (two dispatches, proven 334.9 total / 146.6 bp: stride ≡ 2 mod 4
// + b64 check LDS + iter-0 peel + xor-sign + exact-degree dispatch) with one
// register/I-cache relief:
//  - R13 post-mortem: fused per-block setup cost +42 us GPU (> the 23 us
//    dispatch it saved); 2-dispatch structure is the optimum of that
//    trade-space (R7: +3 dispatches = +85 us; R13: fused = +42 us). Closed.
//  - DROPPED ranged fallbacks do_check<16>/do_check<3> (x[16] live across
//    3 loops, instantiated 4x by the k-loop): degrees 13..16 (~6.5%) and
//    d<=3 (~0.1%) now use do_check_big (LDS re-read, no register cache).
//    Cuts peak register pressure + I-cache; targets R12's ~10 MB residual
//    spill signature (WRITE_SIZE 26.6 vs 16.4 MB outputs) at the pinned
//    64 VGPRs. Cost: ~2x LDS reads on 6.6% of checks (~+1-2 us); gain:
//    spill traffic reduction.
//  - Everything else BYTE-IDENTICAL to R12. Bit-exactness class unchanged
//    (xor-sign validated R9-R12; tie rule verbatim; var sum order verbatim).
//  - HARD CONSTRAINTS: 64-VGPR allocator pin (R3/R9); never reorder
//    reference FP math (R6); 2 dispatches minimum (R7/R8/R13).

#define BLOCK 1024
#define NV    8192          // N variables
#define MC    4096          // M checks
#define NE    32768         // E edges (N * DV, DV=4)
#define VPT   (NV / BLOCK)  // 8 vars per thread
#define CPT   (MC / BLOCK)  // 4 checks per thread
#define NITER 10
#define ALPHA 0.8f
#define CLAMP 20.0f
#define MSGW  40896         // padded arena words (159.9 KB)
#define SGNB  0x80000000

// ws layout (ints), 32 KB:
//  [0 .. MC)   : pbase(16b) | deg<<16   (degree-sorted order)
//  [MC .. 2MC) : original check index   (for syndrome + check_adj lookup)

// stride: smallest s >= d with s ≡ 2 (mod 4)  [even base for b64 + banking]
__device__ __forceinline__ int pad_stride(int d) { return d + ((2 - (d & 3)) & 3); }

// ---------------- setup: counting-sort + padded prefix (proven) ----------------
__global__ __launch_bounds__(BLOCK)
void setup_sort(const float* __restrict__ check_mask,
                const int*   __restrict__ check_adj,
                int max_dc, int* __restrict__ ws)
{
    __shared__ int hist[64], cbase[64], wsum[16];
    __shared__ int sdeg[MC];
    const int t = threadIdx.x;
    if (t < 64) hist[t] = 0;
    __syncthreads();
    int deg[CPT];
#pragma unroll
    for (int k = 0; k < CPT; ++k) {
        const int c = t + k * BLOCK;
        int d = 0;
        for (int j = 0; j < max_dc; ++j)
            d += (check_mask[(size_t)c * max_dc + j] != 0.0f) ? 1 : 0;
        deg[k] = d;
        atomicAdd(&hist[d & 63], 1);
    }
    __syncthreads();
    if (t == 0) {
        int s = 0;
        for (int i = 0; i < 64; ++i) { cbase[i] = s; s += hist[i]; }
    }
    __syncthreads();
#pragma unroll
    for (int k = 0; k < CPT; ++k) {
        const int pos = atomicAdd(&cbase[deg[k] & 63], 1);
        sdeg[pos]    = deg[k];
        ws[MC + pos] = t + k * BLOCK;
    }
    __syncthreads();
    int psz[CPT];
    int s = 0;
#pragma unroll
    for (int k = 0; k < CPT; ++k) {
        const int d = sdeg[4 * t + k];
        psz[k] = s;
        s += pad_stride(d);             // even, ≡2 mod 4
    }
    const int lane = t & 63, wv = t >> 6;
    int run = s;
#pragma unroll
    for (int off = 1; off < 64; off <<= 1) {
        const int n = __shfl_up(run, off, 64);
        if (lane >= off) run += n;
    }
    if (lane == 63) wsum[wv] = run;
    __syncthreads();
    if (t == 0) {
        int acc = 0;
        for (int w = 0; w < 16; ++w) { const int v = wsum[w]; wsum[w] = acc; acc += v; }
    }
    __syncthreads();
    const int tb = wsum[wv] + (run - s);
#pragma unroll
    for (int k = 0; k < CPT; ++k) {
        const int i = 4 * t + k;
        ws[i] = ((tb + psz[k]) & 0xFFFF) | (sdeg[i] << 16);
    }
}

// Exact-degree check update, b64 vectorized, byte-base addressing.
// ssb = syndrome sign bit (bit31). Bit-exact vs reference (validated R9-R12).
template<int D>
__device__ __forceinline__ void do_check_x(char* __restrict__ mb,
                                           int stB, int ssb, float pad)
{
    float x[D];
    constexpr int P = D / 2;
#pragma unroll
    for (int p = 0; p < P; ++p) {
        const float2 r = *(const float2*)(mb + stB + 8 * p);
        x[2 * p]     = r.x;
        x[2 * p + 1] = r.y;
    }
    if constexpr (D & 1)
        x[D - 1] = *(const float*)(mb + stB + 4 * (D - 1));

    float min1 = pad, min2 = pad;
    int sb = ssb;
#pragma unroll
    for (int j = 0; j < D; ++j) {
        sb ^= __float_as_int(x[j]);                     // sign parity (no -0.0)
        const float a = fabsf(x[j]);
        min2 = __builtin_amdgcn_fmed3f(min1, min2, a);  // uses OLD min1
        min1 = fminf(min1, a);
    }
    const float vm1 = ALPHA * min1;
    const float vm2 = ALPHA * min2;
#pragma unroll
    for (int p = 0; p < P; ++p) {
        const int j0 = 2 * p, j1 = 2 * p + 1;
        const float m0 = (fabsf(fabsf(x[j0]) - min1) < 1e-9f) ? vm2 : vm1;  // REF tie rule
        const float m1 = (fabsf(fabsf(x[j1]) - min1) < 1e-9f) ? vm2 : vm1;
        float2 w;
        w.x = __int_as_float(__float_as_int(m0) | ((sb ^ __float_as_int(x[j0])) & SGNB));
        w.y = __int_as_float(__float_as_int(m1) | ((sb ^ __float_as_int(x[j1])) & SGNB));
        *(float2*)(mb + stB + 8 * p) = w;
    }
    if constexpr (D & 1) {
        const int jt = D - 1;
        const float mt = (fabsf(fabsf(x[jt]) - min1) < 1e-9f) ? vm2 : vm1;
        *(float*)(mb + stB + 4 * jt) =
            __int_as_float(__float_as_int(mt) | ((sb ^ __float_as_int(x[jt])) & SGNB));
    }
}

// Generic fallback (LDS re-read, no register cache): d<=3, 13..16, >16, d==0.
__device__ void do_check_big(char* __restrict__ mb,
                             int stB, int d, int ssb, float pad)
{
    float min1 = pad, min2 = pad;
    int sb = ssb;
    for (int j = 0; j < d; ++j) {
        const float xx = *(const float*)(mb + stB + 4 * j);
        sb ^= __float_as_int(xx);
        const float aa = fabsf(xx);
        min2 = __builtin_amdgcn_fmed3f(min1, min2, aa);
        min1 = fminf(min1, aa);
    }
    const float vm1 = ALPHA * min1;
    const float vm2 = ALPHA * min2;
    for (int j = 0; j < d; ++j) {
        const float xx = *(const float*)(mb + stB + 4 * j);
        const float m  = (fabsf(fabsf(xx) - min1) < 1e-9f) ? vm2 : vm1;
        *(float*)(mb + stB + 4 * j) =
            __int_as_float(__float_as_int(m) | ((sb ^ __float_as_int(xx)) & SGNB));
    }
}

// Check phase for one k-step: exact-degree tree (wave-coherent after sort).
__device__ __forceinline__ void check_dispatch(char* __restrict__ mb,
                                               int stB, int d, int ssb, float pad)
{
    if      (d == 8)  do_check_x<8>(mb, stB, ssb, pad);
    else if (d == 7)  do_check_x<7>(mb, stB, ssb, pad);
    else if (d == 9)  do_check_x<9>(mb, stB, ssb, pad);
    else if (d == 6)  do_check_x<6>(mb, stB, ssb, pad);
    else if (d == 10) do_check_x<10>(mb, stB, ssb, pad);
    else if (d == 5)  do_check_x<5>(mb, stB, ssb, pad);
    else if (d == 11) do_check_x<11>(mb, stB, ssb, pad);
    else if (d == 12) do_check_x<12>(mb, stB, ssb, pad);
    else if (d == 4)  do_check_x<4>(mb, stB, ssb, pad);
    else              do_check_big(mb, stB, d, ssb, pad);   // d<=3, 13.., 0
}

__global__ __launch_bounds__(BLOCK) __attribute__((amdgpu_waves_per_eu(4, 4)))
void bp_decode(const float* __restrict__ syndrome,    // (B, M)
               const float* __restrict__ llr_g,       // (B, N)
               const int*   __restrict__ var_adj,     // (N, 4)
               const int*   __restrict__ var_idx,     // (E,)
               const int*   __restrict__ check_adj,   // (M, max_dc)
               int max_dc,
               const int*   __restrict__ ws,          // sorted check info
               float* __restrict__ out,               // marginals | hard | converged
               int B)
{
    __shared__ float msg[MSGW];  // padded arena, in-place ctv/vtc
    __shared__ float sh_e0;      // |vtc[edge 0]| snapshot for reference's pad
    __shared__ int   mism;

    const int b = blockIdx.x;
    const int t = threadIdx.x;
    char* mb = (char*)msg;

    // ---- load sorted-check info; build pos[e] in LDS (aliasing msg) ----
    int cstB[CPT], dsb[CPT];   // byte base; (deg<<1) | syndrome_bit
    {
        int* posL = (int*)msg;
#pragma unroll
        for (int k = 0; k < CPT; ++k) {
            const int i = t + k * BLOCK;
            const int w = ws[i];
            const int c = ws[MC + i];
            const int pb = w & 0xFFFF;
            const int d  = w >> 16;
            cstB[k] = pb << 2;
            const int sb = (syndrome[(size_t)b * MC + c] > 0.5f) ? 1 : 0;
            dsb[k] = (d << 1) | sb;
            const int st = check_adj[(size_t)c * max_dc];  // first edge (contiguous)
            for (int j = 0; j < d; ++j)
                posL[st + j] = pb + j;
        }
    }
    __syncthreads();

    // ---- edge-0 owner info (reference's pad = |vtc[0]| + 1e6) ----
    const int  v0  = var_idx[0];
    const bool own = (t == (v0 & (BLOCK - 1)));      // thread that writes edge 0
    const int  e0B = ((const int*)msg)[0] << 2;      // posL[0] as byte offset

    // ---- var-side padded slots (byte offsets) + LLRs into registers ----
    int   vsB[VPT][4];
    float llr[VPT];
    {
        const int* posL = (const int*)msg;
#pragma unroll
        for (int k = 0; k < VPT; ++k) {
            const int v = t + k * BLOCK;
            const int4 a = ((const int4*)var_adj)[v];   // var degree is exactly 4
            vsB[k][0] = posL[a.x] << 2; vsB[k][1] = posL[a.y] << 2;
            vsB[k][2] = posL[a.z] << 2; vsB[k][3] = posL[a.w] << 2;
            llr[k] = llr_g[(size_t)b * NV + v];
        }
    }
    __syncthreads();   // posL reads done; msg may now be overwritten (no zero-fill:
                       // iter 0 writes every edge slot; pad gaps are never read)

    // ======== iter 0 (peeled): ctv==0 -> vtc = clip(llr), write-only ========
#pragma unroll
    for (int k = 0; k < VPT; ++k) {
        const float o = __builtin_amdgcn_fmed3f(llr[k], -CLAMP, CLAMP);
        *(float*)(mb + vsB[k][0]) = o;
        *(float*)(mb + vsB[k][1]) = o;
        *(float*)(mb + vsB[k][2]) = o;
        *(float*)(mb + vsB[k][3]) = o;
    }
    if (own) sh_e0 = fabsf(*(const float*)(mb + e0B)) + 1.0e6f;  // own write, RAW-ordered
    __syncthreads();
    {
        const float pad = sh_e0;
#pragma unroll
        for (int k = 0; k < CPT; ++k)
            check_dispatch(mb, cstB[k], dsb[k] >> 1, (dsb[k] & 1) << 31, pad);
    }
    __syncthreads();

    // ======== iters 1..NITER-1 ========
#pragma unroll 1
    for (int it = 1; it < NITER; ++it) {
        // ---- variable phase: msg(ctv) -> msg(vtc), in place ----
#pragma unroll
        for (int k = 0; k < VPT; ++k) {
            const float c0 = *(const float*)(mb + vsB[k][0]);
            const float c1 = *(const float*)(mb + vsB[k][1]);
            const float c2 = *(const float*)(mb + vsB[k][2]);
            const float c3 = *(const float*)(mb + vsB[k][3]);
            const float tot  = ((c0 + c1) + c2) + c3;   // reference sum order
            const float bse  = llr[k] + tot;
            *(float*)(mb + vsB[k][0]) = __builtin_amdgcn_fmed3f(bse - c0, -CLAMP, CLAMP);
            *(float*)(mb + vsB[k][1]) = __builtin_amdgcn_fmed3f(bse - c1, -CLAMP, CLAMP);
            *(float*)(mb + vsB[k][2]) = __builtin_amdgcn_fmed3f(bse - c2, -CLAMP, CLAMP);
            *(float*)(mb + vsB[k][3]) = __builtin_amdgcn_fmed3f(bse - c3, -CLAMP, CLAMP);
        }
        if (own) sh_e0 = fabsf(*(const float*)(mb + e0B)) + 1.0e6f;   // own write, ordered
        __syncthreads();
        const float pad = sh_e0;

        // ---- check phase: contiguous padded regions, b64 pairs ----
#pragma unroll
        for (int k = 0; k < CPT; ++k)
            check_dispatch(mb, cstB[k], dsb[k] >> 1, (dsb[k] & 1) << 31, pad);
        __syncthreads();
    }

    // ---- finale: marginals, hard decisions, convergence ----
    float marg[VPT], hard[VPT];
#pragma unroll
    for (int k = 0; k < VPT; ++k) {
        const float c0 = *(const float*)(mb + vsB[k][0]);
        const float c1 = *(const float*)(mb + vsB[k][1]);
        const float c2 = *(const float*)(mb + vsB[k][2]);
        const float c3 = *(const float*)(mb + vsB[k][3]);
        const float tot = ((c0 + c1) + c2) + c3;
        const float tl  = llr[k] + tot;
        const float mg  = 1.0f / (1.0f + expf(tl));   // sigmoid(-tl)
        marg[k] = mg;
        hard[k] = (mg > 0.5f) ? 1.0f : 0.0f;
    }
    if (t == 0) mism = 0;
    __syncthreads();   // all ctv reads done; safe to overwrite msg

    const size_t BN = (size_t)B * NV;
#pragma unroll
    for (int k = 0; k < VPT; ++k) {
        const int v = t + k * BLOCK;
        out[(size_t)b * NV + v]      = marg[k];        // output 0: marginals
        out[BN + (size_t)b * NV + v] = hard[k];        // output 1: hard_decision
        const float h = hard[k];                       // scatter hard bit to edges
        *(float*)(mb + vsB[k][0]) = h;
        *(float*)(mb + vsB[k][1]) = h;
        *(float*)(mb + vsB[k][2]) = h;
        *(float*)(mb + vsB[k][3]) = h;
    }
    __syncthreads();

    // syn_hat[c] = parity over the check's edges' hard bits; converged iff == syndrome
#pragma unroll
    for (int k = 0; k < CPT; ++k) {
        const int d  = dsb[k] >> 1;
        const int sb = dsb[k] & 1;
        int par = 0;
        for (int j = 0; j < d; ++j)
            par ^= (*(const float*)(mb + cstB[k] + 4 * j) != 0.0f) ? 1 : 0;
        if (par != sb) mism = 1;   // benign race: all writers store 1
    }
    __syncthreads();
    if (t == 0) out[2 * BN + b] = mism ? 0.0f : 1.0f;  // output 2: converged
}

extern "C" void kernel_launch(void* const* d_in, const int* in_sizes, int n_in,
                              void* d_out, int out_size, void* d_ws, size_t ws_size,
                              hipStream_t stream) {
    const float* syndrome   = (const float*)d_in[0];
    const float* llr        = (const float*)d_in[1];
    const int*   var_adj    = (const int*)d_in[2];
    // d_in[3] var_adj_mask: all ones (DV=4 exact) — unused
    const int*   check_adj  = (const int*)d_in[4];
    const float* check_mask = (const float*)d_in[5];
    const int*   var_idx    = (const int*)d_in[6];
    // d_in[7] pcm_dense — unused
    float* out = (float*)d_out;
    int*   ws  = (int*)d_ws;    // needs 2*MC ints = 32 KB (proven size)

    const int B      = in_sizes[0] / MC;      // 256
    const int max_dc = in_sizes[4] / MC;

    setup_sort<<<1, BLOCK, 0, stream>>>(check_mask, check_adj, max_dc, ws);
    bp_decode<<<B, BLOCK, 0, stream>>>(syndrome, llr, var_adj, var_idx,
                                       check_adj, max_dc, ws, out, B);
}